// Round 2
// baseline (779.748 us; speedup 1.0000x reference)
//
#include <hip/hip_runtime.h>

#define BB 4096
#define CC 32000
#define CPAD 32768             // padded column count (zeros beyond CC)
#define QR (CC / 4)            // 8000 quads per row

#define NT1 256                // pass1: one block per row
#define NIT1 ((QR + NT1 - 1) / NT1)  // 32 iterations (last is wave-uniform partial)

#define NT2 512                // pass2: 1 quad per thread, 2048-col slab
#define NCB (CPAD / (NT2 * 4)) // 16 column blocks
#define NRB 128                // row blocks
#define RSLAB (BB / NRB)       // 32 rows per slab
#define NP NRB                 // number of partial slabs

#define FBLK (CPAD / 4 / 256)  // 32 finalize blocks, exactly CPAD/4 quads

typedef float v4f __attribute__((ext_vector_type(4)));

// ---- Pass 1: rcpZ[r] = 1 / sum_c exp(x[r,c]); fused bincount.
// One block per row, pure streaming read, no inter-block coupling.
__global__ __launch_bounds__(NT1) void pass1_z(const float* __restrict__ x,
                                               const int* __restrict__ tgt,
                                               float* __restrict__ rcpZ,
                                               float* __restrict__ counts) {
    const int t = threadIdx.x;
    const int r = blockIdx.x;
    const float* rp = x + (size_t)r * CC;

    float s = 0.f;
#pragma unroll 4
    for (int i = 0; i < NIT1; ++i) {
        const int q = i * NT1 + t;
        if (q < QR) {  // i<31 always true; i=31 active iff t<64 (wave-uniform)
            v4f v = *(const v4f*)(rp + 4 * q);
            s += __expf(v.x) + __expf(v.y) + __expf(v.z) + __expf(v.w);
        }
    }
    // wave reduce
    for (int off = 32; off > 0; off >>= 1) s += __shfl_down(s, off);
    __shared__ float red[NT1 / 64];
    if ((t & 63) == 0) red[t >> 6] = s;
    __syncthreads();
    if (t == 0) {
        float z = 0.f;
#pragma unroll
        for (int w = 0; w < NT1 / 64; ++w) z += red[w];
        rcpZ[r] = 1.0f / z;
        atomicAdd(&counts[tgt[r]], 1.0f);  // one atomic per row
    }
}

// ---- Pass 2: per (row-slab, col-slice) block, accumulate exp(x)*rcpZ[r] into a
// single v4f per thread over 32 rows. No barriers, no cross-thread traffic.
__global__ __launch_bounds__(NT2) void pass2_acc(const float* __restrict__ x,
                                                 const float* __restrict__ rcpZ,
                                                 float* __restrict__ partial) {
    const int t = threadIdx.x;
    const int cb = blockIdx.x & (NCB - 1);   // consecutive blocks -> same row slab,
    const int rb = blockIdx.x / NCB;         // adjacent 8KB col chunks (DRAM locality)
    const int col = cb * (NT2 * 4) + 4 * t;  // CPAD-space column
    const int r0 = rb * RSLAB;

    v4f acc = {0.f, 0.f, 0.f, 0.f};
    if (col < CC) {  // slab 15 cutoff at t==320 (5 full waves idle) -> wave-uniform
        const float* p = x + (size_t)r0 * CC + col;
#pragma unroll 8
        for (int r = 0; r < RSLAB; ++r) {
            v4f v = *(const v4f*)(p + (size_t)r * CC);
            const float rz = rcpZ[r0 + r];  // block-uniform -> scalar load, L2-hot
            acc.x += __expf(v.x) * rz;
            acc.y += __expf(v.y) * rz;
            acc.z += __expf(v.z) * rz;
            acc.w += __expf(v.w) * rz;
        }
    }
    // pad region [CC, CPAD) written as zeros (acc untouched there)
    *(v4f*)(partial + (size_t)rb * CPAD + col) = acc;
}

// ---- Finalize: loss = (1/(B*C)) * sum_c | sum_slab partial[slab][c] - counts[c] |
__global__ __launch_bounds__(256) void finalize(const float* __restrict__ partial,
                                                const float* __restrict__ counts,
                                                float* __restrict__ total,
                                                unsigned* __restrict__ blkcnt,
                                                float* __restrict__ out) {
    const int g = blockIdx.x * 256 + threadIdx.x;  // quad index, < CPAD/4 exactly
    v4f s = {0.f, 0.f, 0.f, 0.f};
    const v4f* pv = (const v4f*)partial;
#pragma unroll 4
    for (int b = 0; b < NP; ++b) {
        v4f p = pv[(size_t)b * (CPAD / 4) + g];
        s.x += p.x; s.y += p.y; s.z += p.z; s.w += p.w;
    }
    float v = 0.f;
    const int c = 4 * g;
    if (c < CC) {  // CC % 4 == 0, so c+3 < CC too; pad quads contribute 0
        v4f cnt = *(const v4f*)(counts + c);
        v = fabsf(s.x - cnt.x) + fabsf(s.y - cnt.y) + fabsf(s.z - cnt.z) + fabsf(s.w - cnt.w);
    }
    for (int off = 32; off > 0; off >>= 1) v += __shfl_down(v, off);
    __shared__ float wsum[4];
    if ((threadIdx.x & 63) == 0) wsum[threadIdx.x >> 6] = v;
    __syncthreads();
    if (threadIdx.x == 0) {
        atomicAdd(total, wsum[0] + wsum[1] + wsum[2] + wsum[3]);
        __threadfence();
        unsigned prev = atomicAdd(blkcnt, 1u);
        if (prev == FBLK - 1) {
            float tot = atomicAdd(total, 0.0f);  // device-scope read of final value
            out[0] = tot * (1.0f / ((float)BB * (float)CC));
        }
    }
}

extern "C" void kernel_launch(void* const* d_in, const int* in_sizes, int n_in,
                              void* d_out, int out_size, void* d_ws, size_t ws_size,
                              hipStream_t stream) {
    const float* x = (const float*)d_in[0];
    const int* tgt = (const int*)d_in[1];
    float* out = (float*)d_out;

    // ws layout (floats): partial[NP*CPAD] | counts[CC] | total | blkcnt | rcpZ[BB]
    float* partial = (float*)d_ws;                 // 16,777,216 B
    float* counts = partial + (size_t)NP * CPAD;
    float* total = counts + CC;
    unsigned* blkcnt = (unsigned*)(total + 1);
    float* rcpZ = (float*)(blkcnt + 1);

    (void)hipMemsetAsync(counts, 0, (size_t)(CC + 2) * 4, stream);

    pass1_z<<<BB, NT1, 0, stream>>>(x, tgt, rcpZ, counts);
    pass2_acc<<<NCB * NRB, NT2, 0, stream>>>(x, rcpZ, partial);
    finalize<<<FBLK, 256, 0, stream>>>(partial, counts, total, blkcnt, out);
}

// Round 3
// 651.781 us; speedup vs baseline: 1.1963x; 1.1963x over previous
//
#include <hip/hip_runtime.h>

#define BB 4096
#define CC 32000
#define CPAD 32768           // padded column count (zeros beyond CC)
#define NT 512               // threads per block
#define NI 16                // float4 chunks per thread: NT*4*NI = CPAD
#define GRID 256             // one block per CU (LDS 128 KB -> 1 block/CU)
#define RPB (BB / GRID)      // 16 rows per block
#define FBLK 32              // finalize blocks: 32*256 threads = CPAD/4 quads exactly

typedef float v4f __attribute__((ext_vector_type(4)));

// ---- Single pass: read x once; per row exp->Z->scale, accumulate conf sums in LDS.
__global__ __launch_bounds__(NT, 2) void mdca_main(const float* __restrict__ x,
                                                   const int* __restrict__ tgt,
                                                   float* __restrict__ partial,
                                                   float* __restrict__ counts) {
    __shared__ float acc[CPAD];   // 128 KB: acc[c] = sum_r exp(x[r,c])/Z_r (block's rows)
    __shared__ float red[NT / 64];
    __shared__ float s_rcp;

    const int t = threadIdx.x;
    const int r0 = blockIdx.x * RPB;

    // zero the accumulator
    for (int i = t; i < CPAD / 4; i += NT) ((v4f*)acc)[i] = (v4f){0.f, 0.f, 0.f, 0.f};

    v4f cur[NI], nxt[NI];

    // preload row r0 into registers (thread t owns cols i*2048 + 4t .. +3)
    {
        const float* rp = x + (size_t)r0 * CC;
#pragma unroll
        for (int i = 0; i < NI; ++i) {
            const int col = i * 2048 + 4 * t;
            if (col < CC) cur[i] = __builtin_nontemporal_load((const v4f*)(rp + col));
        }
    }
    __syncthreads();  // acc zeros visible

    for (int r = 0; r < RPB; ++r) {
        // issue next row's loads FIRST so HBM stays busy through the barriers
        if (r + 1 < RPB) {
            const float* rp = x + (size_t)(r0 + r + 1) * CC;
#pragma unroll
            for (int i = 0; i < NI; ++i) {
                const int col = i * 2048 + 4 * t;
                if (col < CC) nxt[i] = __builtin_nontemporal_load((const v4f*)(rp + col));
            }
        }
        // exp current row in-register; partial sum
        float s = 0.f;
#pragma unroll
        for (int i = 0; i < NI; ++i) {
            const int col = i * 2048 + 4 * t;
            if (col < CC) {
                v4f e;
                e.x = __expf(cur[i].x); e.y = __expf(cur[i].y);
                e.z = __expf(cur[i].z); e.w = __expf(cur[i].w);
                cur[i] = e;
                s += e.x + e.y + e.z + e.w;
            }
        }
        // block reduce -> rcpZ
        for (int off = 32; off > 0; off >>= 1) s += __shfl_down(s, off);
        if ((t & 63) == 0) red[t >> 6] = s;
        __syncthreads();
        if (t == 0) {
            float z = 0.f;
#pragma unroll
            for (int w = 0; w < NT / 64; ++w) z += red[w];
            s_rcp = 1.0f / z;
        }
        __syncthreads();
        const float rz = s_rcp;
        // scale-accumulate into LDS (each thread owns its acc slots -> no races,
        // contiguous 16B per lane -> conflict-free ds_read/write_b128)
#pragma unroll
        for (int i = 0; i < NI; ++i) {
            const int col = i * 2048 + 4 * t;
            if (col < CC) {
                v4f a = ((v4f*)acc)[i * 512 + t];
                a.x += cur[i].x * rz; a.y += cur[i].y * rz;
                a.z += cur[i].z * rz; a.w += cur[i].w * rz;
                ((v4f*)acc)[i * 512 + t] = a;
            }
        }
        // rotate register buffers
        if (r + 1 < RPB) {
#pragma unroll
            for (int i = 0; i < NI; ++i) cur[i] = nxt[i];
        }
        // no barrier needed here: acc slots are thread-private; red/s_rcp reuse is
        // ordered by the two barriers above (writers of red(r+1) passed bar2(r),
        // which is after all red(r) reads; s_rcp(r+1) write is after bar1(r+1)).
    }

    // write this block's column partials (thread-private slots; no barrier needed)
    v4f* pp = (v4f*)(partial + (size_t)blockIdx.x * CPAD);
#pragma unroll
    for (int i = 0; i < NI; ++i) {
        const int col = i * 2048 + 4 * t;
        v4f a = (col < CC) ? ((v4f*)acc)[i * 512 + t] : (v4f){0.f, 0.f, 0.f, 0.f};
        pp[i * 512 + t] = a;
    }
    // fused bincount: one atomic per row
    if (t < RPB) atomicAdd(&counts[tgt[r0 + t]], 1.0f);
}

// ---- Finalize: loss = (1/(B*C)) * sum_c | sum_b partial[b][c] - counts[c] |
__global__ __launch_bounds__(256) void finalize(const float* __restrict__ partial,
                                                const float* __restrict__ counts,
                                                float* __restrict__ total,
                                                unsigned* __restrict__ blkcnt,
                                                float* __restrict__ out) {
    const int g = blockIdx.x * 256 + threadIdx.x;  // quad index, < CPAD/4 exactly
    v4f s = {0.f, 0.f, 0.f, 0.f};
    const v4f* pv = (const v4f*)partial;
    for (int b = 0; b < GRID; ++b) {
        v4f p = pv[(size_t)b * (CPAD / 4) + g];
        s.x += p.x; s.y += p.y; s.z += p.z; s.w += p.w;
    }
    float v = 0.f;
    const int c = 4 * g;
    if (c < CC) {  // c+3 < CC too (CC % 4 == 0); padded quads contribute 0
        v4f cnt = *(const v4f*)(counts + c);
        v = fabsf(s.x - cnt.x) + fabsf(s.y - cnt.y) + fabsf(s.z - cnt.z) + fabsf(s.w - cnt.w);
    }
    for (int off = 32; off > 0; off >>= 1) v += __shfl_down(v, off);
    __shared__ float wsum[4];
    if ((threadIdx.x & 63) == 0) wsum[threadIdx.x >> 6] = v;
    __syncthreads();
    if (threadIdx.x == 0) {
        atomicAdd(total, wsum[0] + wsum[1] + wsum[2] + wsum[3]);
        __threadfence();
        unsigned prev = atomicAdd(blkcnt, 1u);
        if (prev == FBLK - 1) {
            float tot = atomicAdd(total, 0.0f);  // device-scope read of final value
            out[0] = tot * (1.0f / ((float)BB * (float)CC));
        }
    }
}

extern "C" void kernel_launch(void* const* d_in, const int* in_sizes, int n_in,
                              void* d_out, int out_size, void* d_ws, size_t ws_size,
                              hipStream_t stream) {
    const float* x = (const float*)d_in[0];
    const int* tgt = (const int*)d_in[1];
    float* out = (float*)d_out;

    // ws layout (floats): partial[GRID*CPAD] | counts[CC] | total | blkcnt
    float* partial = (float*)d_ws;                       // 33,554,432 B
    float* counts = partial + (size_t)GRID * CPAD;
    float* total = counts + CC;
    unsigned* blkcnt = (unsigned*)(total + 1);

    (void)hipMemsetAsync(counts, 0, (size_t)(CC + 2) * 4, stream);

    mdca_main<<<GRID, NT, 0, stream>>>(x, tgt, partial, counts);
    finalize<<<FBLK, 256, 0, stream>>>(partial, counts, total, blkcnt, out);
}